// Round 4
// baseline (103.823 us; speedup 1.0000x reference)
//
#include <hip/hip_runtime.h>
#include <hip/hip_bf16.h>
#include <stdint.h>

#define GAS __attribute__((address_space(1)))
#define LAS __attribute__((address_space(3)))

typedef __attribute__((ext_vector_type(8))) short bf16x8;
typedef __attribute__((ext_vector_type(4))) float f32x4;

struct us4 { unsigned short x, y, z, w; };

__device__ __forceinline__ void gl_lds16(const void* g, void* lds) {
  __builtin_amdgcn_global_load_lds((const GAS unsigned int*)(uintptr_t)g,
                                   (LAS unsigned int*)(uintptr_t)lds, 16, 0, 0);
}

__device__ __forceinline__ unsigned short f2bf(float f) {
  unsigned u = __float_as_uint(f);
  return (unsigned short)((u + 0x7fffu + ((u >> 16) & 1u)) >> 16);
}

// ---------------- Threefry2x32 (JAX key = (0, 42)) ----------------
__device__ __forceinline__ void threefry2x32_42(unsigned x0, unsigned x1,
                                                unsigned* o0, unsigned* o1) {
  const unsigned k0 = 0u, k1 = 42u;
  unsigned ks[3] = {k0, k1, k0 ^ k1 ^ 0x1BD11BDAu};
  x0 += ks[0]; x1 += ks[1];
  const int rot[2][4] = {{13, 15, 26, 6}, {17, 29, 16, 24}};
#pragma unroll
  for (int i = 0; i < 5; ++i) {
#pragma unroll
    for (int j = 0; j < 4; ++j) {
      int r = rot[i & 1][j];
      x0 += x1;
      x1 = (x1 << r) | (x1 >> (32 - r));
      x1 ^= x0;
    }
    x0 += ks[(i + 1) % 3];
    x1 += ks[(i + 2) % 3] + (unsigned)(i + 1);
  }
  *o0 = x0; *o1 = x1;
}

// ---------------- k1: fused pooled-logit partials + X -> bf16 ----------------
// grid (8, 32): blockIdx.y = batch b, blockIdx.x = chunk c (64 S-rows each)
__global__ __launch_bounds__(256) void k_router_pool(
    const float* __restrict__ X, const float* __restrict__ rw,
    unsigned short* __restrict__ Xbf, float* __restrict__ partial) {
  __shared__ float srw[4 * 768];
  int t = threadIdx.x;
  int b = blockIdx.y, c = blockIdx.x;
  for (int q = t; q < 3072; q += 256) srw[q] = rw[q];
  __syncthreads();
  const float* xp = X + (size_t)b * 393216 + (size_t)c * 49152;
  unsigned short* xo = Xbf + (size_t)b * 393216 + (size_t)c * 49152;
  float a0 = 0.f, a1 = 0.f, a2 = 0.f, a3 = 0.f;
  for (int it = 0; it < 48; ++it) {
    int off = it * 1024 + t * 4;
    float4 v = *reinterpret_cast<const float4*>(xp + off);
    int i0 = ((it * 256 + t) % 192) * 4;
    a0 += v.x * srw[i0] + v.y * srw[i0 + 1] + v.z * srw[i0 + 2] + v.w * srw[i0 + 3];
    a1 += v.x * srw[768 + i0] + v.y * srw[768 + i0 + 1] + v.z * srw[768 + i0 + 2] + v.w * srw[768 + i0 + 3];
    a2 += v.x * srw[1536 + i0] + v.y * srw[1536 + i0 + 1] + v.z * srw[1536 + i0 + 2] + v.w * srw[1536 + i0 + 3];
    a3 += v.x * srw[2304 + i0] + v.y * srw[2304 + i0 + 1] + v.z * srw[2304 + i0 + 2] + v.w * srw[2304 + i0 + 3];
    us4 o;
    o.x = f2bf(v.x); o.y = f2bf(v.y); o.z = f2bf(v.z); o.w = f2bf(v.w);
    *reinterpret_cast<us4*>(xo + off) = o;
  }
#pragma unroll
  for (int off = 32; off > 0; off >>= 1) {
    a0 += __shfl_down(a0, off);
    a1 += __shfl_down(a1, off);
    a2 += __shfl_down(a2, off);
    a3 += __shfl_down(a3, off);
  }
  __shared__ float red[4][4];
  int w = t >> 6;
  if ((t & 63) == 0) { red[w][0] = a0; red[w][1] = a1; red[w][2] = a2; red[w][3] = a3; }
  __syncthreads();
  if (t < 4) {
    float s = red[0][t] + red[1][t] + red[2][t] + red[3][t];
    partial[(b * 8 + c) * 4 + t] = s;
  }
}

// ---------------- k1b: finish logits, gumbel argmax -> expert[32] ----------------
// JAX partitionable threefry (jax/_src/prng.py _threefry_random_bits_partitionable):
//   counts = iota(uint64); hi = counts>>32 (=0), lo = counts
//   bits1, bits2 = threefry2x32(key, (hi, lo))
//   for bit_width==32: bits = bits1 ^ bits2   <-- XOR fold, not truncation
__global__ __launch_bounds__(128) void k_router_pick(
    const float* __restrict__ partial, const float* __restrict__ rb,
    int* __restrict__ expert) {
  __shared__ float lg[128];
  int t = threadIdx.x;
  int b = t >> 2, e = t & 3;
  float s = 0.f;
#pragma unroll
  for (int c = 0; c < 8; ++c) s += partial[(b * 8 + c) * 4 + e];
  lg[t] = s * (1.0f / 512.0f) + rb[e];
  __syncthreads();
  if (t < 32) {
    int bb = t;
    float best = -1e30f; int bi = 0;
#pragma unroll
    for (int ee = 0; ee < 4; ++ee) {
      int idx = bb * 4 + ee;
      unsigned x0, x1;
      threefry2x32_42(0u, (unsigned)idx, &x0, &x1);
      unsigned bits = x0 ^ x1;  // <-- XOR fold of the 64-bit cipher block
      float u01 = __uint_as_float((bits >> 9) | 0x3f800000u) - 1.0f;
      float u = u01 * ((1.0f - 1e-6f) - 1e-6f) + 1e-6f;
      u = fmaxf(u, 1e-6f);
      float g = -logf(-logf(u));
      float v = lg[bb * 4 + ee] + g;
      if (v > best) { best = v; bi = ee; }
    }
    expert[bb] = bi;
  }
}

// ---------------- k2a: TT core contraction -> Kmat[e][768][8], Lt[e][768][8] ----------------
__global__ __launch_bounds__(256) void k_build_kl(
    const float* __restrict__ c0, const float* __restrict__ c1,
    const float* __restrict__ c2, const float* __restrict__ c3,
    const float* __restrict__ c4, const float* __restrict__ c5,
    float* __restrict__ Kmat, float* __restrict__ Lt) {
  int e = blockIdx.x, t = threadIdx.x;
  __shared__ float KA[768];  // [96 (a1*12+a0)][8 p2]
  __shared__ float LB[768];  // [8 p4][96 (n2*12+n3)]
  for (int q = t; q < 768; q += 256) {
    int bc = q >> 3, p2 = q & 7;
    int b2 = bc / 12, cc = bc % 12;
    float s = 0.f;
#pragma unroll
    for (int p1 = 0; p1 < 8; ++p1)
      s += c0[e * 96 + cc * 8 + p1] * c1[((e * 8 + p1) * 8 + b2) * 8 + p2];
    KA[q] = s;
    int p4 = q / 96, mm = q % 96;
    int n2 = mm / 12, n3 = mm % 12;
    float s2 = 0.f;
#pragma unroll
    for (int p5 = 0; p5 < 8; ++p5)
      s2 += c4[((e * 8 + p4) * 8 + n2) * 8 + p5] * c5[(e * 8 + p5) * 12 + n3];
    LB[q] = s2;
  }
  __syncthreads();
  for (int q = t; q < 6144; q += 256) {
    int i = q >> 3, p3 = q & 7;
    int a = i / 96, bc = i % 96;
    float s = 0.f;
#pragma unroll
    for (int p2 = 0; p2 < 8; ++p2)
      s += KA[bc * 8 + p2] * c2[((e * 8 + p2) * 8 + a) * 8 + p3];
    Kmat[e * 6144 + q] = s;
    int n1 = i / 96, mm = i % 96;
    float s2 = 0.f;
#pragma unroll
    for (int p4 = 0; p4 < 8; ++p4)
      s2 += c3[((e * 8 + p3) * 8 + n1) * 8 + p4] * LB[p4 * 96 + mm];
    Lt[e * 6144 + q] = s2;
  }
}

// ---------------- k2b: Wbt[e][j(N)][i(K)] = bf16(base_w[j][i] + 16 * K[i,:].Lt[j,:]) ----------------
__global__ __launch_bounds__(256) void k_build_w(
    const float* __restrict__ bw, const float* __restrict__ Kmat,
    const float* __restrict__ Lt, unsigned short* __restrict__ Wbt) {
  int j = blockIdx.x, e = blockIdx.y, t = threadIdx.x;
  float l[8];
#pragma unroll
  for (int p = 0; p < 8; ++p) l[p] = Lt[e * 6144 + j * 8 + p];
#pragma unroll
  for (int rep = 0; rep < 3; ++rep) {
    int i = t + rep * 256;
    const float* kp = Kmat + e * 6144 + i * 8;
    float s = 0.f;
#pragma unroll
    for (int p = 0; p < 8; ++p) s += kp[p] * l[p];
    float val = bw[j * 768 + i] + 16.0f * s;
    Wbt[(size_t)e * 589824 + (size_t)j * 768 + i] = f2bf(val);
  }
}

// ---------------- k4: bf16 MFMA GEMM, 128x128 tile, BK=64, m97 structure ----------------
// C[t, j] = sum_k Xbf[t, k] * Wbt[e][j][k] + base_b[j]
__global__ __launch_bounds__(256) void k_gemm(
    const unsigned short* __restrict__ Xbf,  // [16384][768]
    const unsigned short* __restrict__ Wbt,  // [4][768][768] (N-major)
    const int* __restrict__ expert,          // [32]
    const float* __restrict__ base_b,        // [768]
    float* __restrict__ out)                 // [16384][768]
{
  __shared__ unsigned short sA[128 * 64];
  __shared__ unsigned short sB[128 * 64];
  int tid = threadIdx.x;
  int w = tid >> 6, l = tid & 63;
  int l16 = l & 15, l4 = l >> 4;
  int mtile = blockIdx.y, ntile = blockIdx.x;
  int m0 = mtile * 128, n0 = ntile * 128;
  int e = expert[mtile >> 2];  // 512 rows per batch, 4 m-tiles per batch
  const unsigned short* Wb = Wbt + (size_t)e * 589824;
  int wr = w >> 1, wc = w & 1;

  f32x4 acc[4][4];
#pragma unroll
  for (int i = 0; i < 4; ++i)
#pragma unroll
    for (int jj = 0; jj < 4; ++jj) acc[i][jj] = (f32x4)0.f;

  // per-issue row/col for staging
  int rows[4], c8s[4];
#pragma unroll
  for (int q = 0; q < 4; ++q) {
    int ci = (w * 4 + q) * 64 + l;
    rows[q] = ci >> 3;
    c8s[q] = (ci & 7) * 8;
  }

  for (int k0 = 0; k0 < 768; k0 += 64) {
#pragma unroll
    for (int q = 0; q < 4; ++q) {
      const unsigned short* ga = Xbf + (size_t)(m0 + rows[q]) * 768 + k0 + c8s[q];
      gl_lds16(ga, &sA[(w * 4 + q) * 512]);
      const unsigned short* gb = Wb + (size_t)(n0 + rows[q]) * 768 + k0 + c8s[q];
      gl_lds16(gb, &sB[(w * 4 + q) * 512]);
    }
    __syncthreads();
#pragma unroll
    for (int kk = 0; kk < 2; ++kk) {
      bf16x8 af[4], bfr[4];
#pragma unroll
      for (int am = 0; am < 4; ++am)
        af[am] = *reinterpret_cast<const bf16x8*>(
            &sA[(wr * 64 + am * 16 + l16) * 64 + kk * 32 + l4 * 8]);
#pragma unroll
      for (int bn = 0; bn < 4; ++bn)
        bfr[bn] = *reinterpret_cast<const bf16x8*>(
            &sB[(wc * 64 + bn * 16 + l16) * 64 + kk * 32 + l4 * 8]);
#pragma unroll
      for (int am = 0; am < 4; ++am)
#pragma unroll
        for (int bn = 0; bn < 4; ++bn)
          acc[am][bn] = __builtin_amdgcn_mfma_f32_16x16x32_bf16(af[am], bfr[bn], acc[am][bn], 0, 0, 0);
    }
    __syncthreads();
  }

  // epilogue: C/D layout col = lane&15, row = (lane>>4)*4 + reg
  float bias[4];
#pragma unroll
  for (int bn = 0; bn < 4; ++bn) bias[bn] = base_b[n0 + wc * 64 + bn * 16 + l16];
#pragma unroll
  for (int am = 0; am < 4; ++am) {
    int rbase = m0 + wr * 64 + am * 16 + l4 * 4;
#pragma unroll
    for (int r = 0; r < 4; ++r) {
      float* op = out + (size_t)(rbase + r) * 768 + n0 + wc * 64 + l16;
#pragma unroll
      for (int bn = 0; bn < 4; ++bn) op[bn * 16] = acc[am][bn][r] + bias[bn];
    }
  }
}

extern "C" void kernel_launch(void* const* d_in, const int* in_sizes, int n_in,
                              void* d_out, int out_size, void* d_ws, size_t ws_size,
                              hipStream_t stream) {
  const float* X  = (const float*)d_in[0];
  const float* rw = (const float*)d_in[1];
  const float* rb = (const float*)d_in[2];
  const float* bw = (const float*)d_in[3];
  const float* bb = (const float*)d_in[4];
  const float* c0 = (const float*)d_in[5];
  const float* c1 = (const float*)d_in[6];
  const float* c2 = (const float*)d_in[7];
  const float* c3 = (const float*)d_in[8];
  const float* c4 = (const float*)d_in[9];
  const float* c5 = (const float*)d_in[10];
  float* out = (float*)d_out;

  char* ws = (char*)d_ws;
  int* expert        = (int*)(ws + 0);              // 128 B
  float* partial     = (float*)(ws + 1024);         // 32*8*4*4 = 4 KB
  float* Kmat        = (float*)(ws + 16384);        // 4*768*8*4 = 96 KB
  float* Lt          = (float*)(ws + 131072);       // 96 KB
  unsigned short* Wbt = (unsigned short*)(ws + 262144);   // 4*768*768*2 = 4.5 MB
  unsigned short* Xbf = (unsigned short*)(ws + 5242880);  // 16384*768*2 = 24 MB

  k_router_pool<<<dim3(8, 32), 256, 0, stream>>>(X, rw, Xbf, partial);
  k_router_pick<<<1, 128, 0, stream>>>(partial, rb, expert);
  k_build_kl<<<4, 256, 0, stream>>>(c0, c1, c2, c3, c4, c5, Kmat, Lt);
  k_build_w<<<dim3(768, 4), 256, 0, stream>>>(bw, Kmat, Lt, Wbt);
  k_gemm<<<dim3(6, 128), 256, 0, stream>>>(Xbf, Wbt, expert, bb, out);
}

// Round 5
// 75.563 us; speedup vs baseline: 1.3740x; 1.3740x over previous
//
#include <hip/hip_runtime.h>
#include <hip/hip_bf16.h>
#include <stdint.h>

#define GAS __attribute__((address_space(1)))
#define LAS __attribute__((address_space(3)))

typedef __attribute__((ext_vector_type(8))) short bf16x8;
typedef __attribute__((ext_vector_type(4))) float f32x4;

struct us4 { unsigned short x, y, z, w; };

__device__ __forceinline__ void gl_lds16(const void* g, void* lds) {
  __builtin_amdgcn_global_load_lds((const GAS unsigned int*)(uintptr_t)g,
                                   (LAS unsigned int*)(uintptr_t)lds, 16, 0, 0);
}

__device__ __forceinline__ unsigned short f2bf(float f) {
  unsigned u = __float_as_uint(f);
  return (unsigned short)((u + 0x7fffu + ((u >> 16) & 1u)) >> 16);
}

// ---------------- Threefry2x32 (JAX key = (0, 42)) ----------------
__device__ __forceinline__ void threefry2x32_42(unsigned x0, unsigned x1,
                                                unsigned* o0, unsigned* o1) {
  const unsigned k0 = 0u, k1 = 42u;
  unsigned ks[3] = {k0, k1, k0 ^ k1 ^ 0x1BD11BDAu};
  x0 += ks[0]; x1 += ks[1];
  const int rot[2][4] = {{13, 15, 26, 6}, {17, 29, 16, 24}};
#pragma unroll
  for (int i = 0; i < 5; ++i) {
#pragma unroll
    for (int j = 0; j < 4; ++j) {
      int r = rot[i & 1][j];
      x0 += x1;
      x1 = (x1 << r) | (x1 >> (32 - r));
      x1 ^= x0;
    }
    x0 += ks[(i + 1) % 3];
    x1 += ks[(i + 2) % 3] + (unsigned)(i + 1);
  }
  *o0 = x0; *o1 = x1;
}

// ---------------- k1: streaming X->bf16 convert + column partial sums ----------------
// 512 blocks: b = blk>>4 (batch), c = blk&15 (chunk of 32 rows). 192 threads, 4 cols each.
__global__ __launch_bounds__(192) void k_router_pool(
    const float* __restrict__ X, unsigned short* __restrict__ Xbf,
    float* __restrict__ partial) {
  int t = threadIdx.x;
  int b = blockIdx.x >> 4, c = blockIdx.x & 15;
  int r0 = b * 512 + c * 32;
  const float* xp = X + (size_t)r0 * 768 + t * 4;
  unsigned short* xo = Xbf + (size_t)r0 * 768 + t * 4;
  float4 acc = {0.f, 0.f, 0.f, 0.f};
#pragma unroll 8
  for (int r = 0; r < 32; ++r) {
    float4 v = *reinterpret_cast<const float4*>(xp + (size_t)r * 768);
    acc.x += v.x; acc.y += v.y; acc.z += v.z; acc.w += v.w;
    us4 o;
    o.x = f2bf(v.x); o.y = f2bf(v.y); o.z = f2bf(v.z); o.w = f2bf(v.w);
    *reinterpret_cast<us4*>(xo + (size_t)r * 768) = o;
  }
  *reinterpret_cast<float4*>(partial + (size_t)blockIdx.x * 768 + t * 4) = acc;
}

// ---------------- k1b: reduce pooled, logits, gumbel argmax -> expert[32] ----------------
// 32 blocks (one per batch) x 256 threads (3 cols each).
__global__ __launch_bounds__(256) void k_router_pick(
    const float* __restrict__ partial, const float* __restrict__ rw,
    const float* __restrict__ rb, int* __restrict__ expert) {
  int t = threadIdx.x, b = blockIdx.x;
  float pooled[3];
#pragma unroll
  for (int j = 0; j < 3; ++j) {
    int col = t + j * 256;
    float s = 0.f;
#pragma unroll
    for (int c = 0; c < 16; ++c) s += partial[(size_t)(b * 16 + c) * 768 + col];
    pooled[j] = s;
  }
  float p[4];
#pragma unroll
  for (int e = 0; e < 4; ++e) {
    float s = 0.f;
#pragma unroll
    for (int j = 0; j < 3; ++j) s += pooled[j] * rw[e * 768 + t + j * 256];
    p[e] = s;
  }
#pragma unroll
  for (int off = 32; off > 0; off >>= 1) {
#pragma unroll
    for (int e = 0; e < 4; ++e) p[e] += __shfl_down(p[e], off);
  }
  __shared__ float red[4][4];
  int w = t >> 6;
  if ((t & 63) == 0) {
#pragma unroll
    for (int e = 0; e < 4; ++e) red[w][e] = p[e];
  }
  __syncthreads();
  if (t == 0) {
    float best = -1e30f; int bi = 0;
#pragma unroll
    for (int e = 0; e < 4; ++e) {
      float s = red[0][e] + red[1][e] + red[2][e] + red[3][e];
      float lg = s * (1.0f / 512.0f) + rb[e];
      int idx = b * 4 + e;
      unsigned x0, x1;
      threefry2x32_42(0u, (unsigned)idx, &x0, &x1);
      unsigned bits = x0 ^ x1;  // partitionable path: XOR fold of cipher block
      float u01 = __uint_as_float((bits >> 9) | 0x3f800000u) - 1.0f;
      float u = u01 * ((1.0f - 1e-6f) - 1e-6f) + 1e-6f;
      u = fmaxf(u, 1e-6f);
      float g = -logf(-logf(u));
      float v = lg + g;
      if (v > best) { best = v; bi = e; }
    }
    expert[b] = bi;
  }
}

// ---------------- k2a: TT core contraction -> Kmat[e][768][8], Lt[e][768][8] ----------------
__global__ __launch_bounds__(256) void k_build_kl(
    const float* __restrict__ c0, const float* __restrict__ c1,
    const float* __restrict__ c2, const float* __restrict__ c3,
    const float* __restrict__ c4, const float* __restrict__ c5,
    float* __restrict__ Kmat, float* __restrict__ Lt) {
  int e = blockIdx.x, t = threadIdx.x;
  __shared__ float KA[768];  // [96 (a1*12+a0)][8 p2]
  __shared__ float LB[768];  // [8 p4][96 (n2*12+n3)]
  for (int q = t; q < 768; q += 256) {
    int bc = q >> 3, p2 = q & 7;
    int b2 = bc / 12, cc = bc % 12;
    float s = 0.f;
#pragma unroll
    for (int p1 = 0; p1 < 8; ++p1)
      s += c0[e * 96 + cc * 8 + p1] * c1[((e * 8 + p1) * 8 + b2) * 8 + p2];
    KA[q] = s;
    int p4 = q / 96, mm = q % 96;
    int n2 = mm / 12, n3 = mm % 12;
    float s2 = 0.f;
#pragma unroll
    for (int p5 = 0; p5 < 8; ++p5)
      s2 += c4[((e * 8 + p4) * 8 + n2) * 8 + p5] * c5[(e * 8 + p5) * 12 + n3];
    LB[q] = s2;
  }
  __syncthreads();
  for (int q = t; q < 6144; q += 256) {
    int i = q >> 3, p3 = q & 7;
    int a = i / 96, bc = i % 96;
    float s = 0.f;
#pragma unroll
    for (int p2 = 0; p2 < 8; ++p2)
      s += KA[bc * 8 + p2] * c2[((e * 8 + p2) * 8 + a) * 8 + p3];
    Kmat[e * 6144 + q] = s;
    int n1 = i / 96, mm = i % 96;
    float s2 = 0.f;
#pragma unroll
    for (int p4 = 0; p4 < 8; ++p4)
      s2 += c3[((e * 8 + p3) * 8 + n1) * 8 + p4] * LB[p4 * 96 + mm];
    Lt[e * 6144 + q] = s2;
  }
}

// ---------------- k2b: Wbt[e][j(N)][i(K)] = bf16(base_w[j][i] + 16 * K[i,:].Lt[j,:]) ----------------
__global__ __launch_bounds__(256) void k_build_w(
    const float* __restrict__ bw, const float* __restrict__ Kmat,
    const float* __restrict__ Lt, unsigned short* __restrict__ Wbt) {
  int j = blockIdx.x, e = blockIdx.y, t = threadIdx.x;
  float l[8];
#pragma unroll
  for (int p = 0; p < 8; ++p) l[p] = Lt[e * 6144 + j * 8 + p];
#pragma unroll
  for (int rep = 0; rep < 3; ++rep) {
    int i = t + rep * 256;
    const float* kp = Kmat + e * 6144 + i * 8;
    float s = 0.f;
#pragma unroll
    for (int p = 0; p < 8; ++p) s += kp[p] * l[p];
    float val = bw[j * 768 + i] + 16.0f * s;
    Wbt[(size_t)e * 589824 + (size_t)j * 768 + i] = f2bf(val);
  }
}

// ---------------- k4: bf16 MFMA GEMM, 128x128, BK=64, dbuf + T2 swizzle + XCD remap ----------
// C[t, j] = sum_k Xbf[t, k] * Wbt[e][j][k] + base_b[j]
__global__ __launch_bounds__(256) void k_gemm(
    const unsigned short* __restrict__ Xbf,  // [16384][768]
    const unsigned short* __restrict__ Wbt,  // [4][768][768] (N-major)
    const int* __restrict__ expert,          // [32]
    const float* __restrict__ base_b,        // [768]
    float* __restrict__ out)                 // [16384][768]
{
  __shared__ unsigned short sA[2][8192];
  __shared__ unsigned short sB[2][8192];
  int tid = threadIdx.x;
  int w = tid >> 6, l = tid & 63;
  int l16 = l & 15, l4 = l >> 4;

  // XCD-locality remap: HW assigns xcd = bid % 8. Give each XCD a contiguous
  // slab of work (96 slots), ntile-fastest so the 6 blocks sharing an A-panel
  // run consecutively on the same XCD.
  int bid = blockIdx.x;
  int work = (bid & 7) * 96 + (bid >> 3);
  int mtile = work / 6, ntile = work - mtile * 6;
  int m0 = mtile * 128, n0 = ntile * 128;
  int e = expert[mtile >> 2];
  const unsigned short* Wb = Wbt + (size_t)e * 589824;
  int wr = w >> 1, wc = w & 1;

  f32x4 acc[4][4];
#pragma unroll
  for (int i = 0; i < 4; ++i)
#pragma unroll
    for (int jj = 0; jj < 4; ++jj) acc[i][jj] = (f32x4)0.f;

  // Staging: LDS dest is linear (slot ci covers row=ci>>3, 16B sub-slot ci&7).
  // T2 swizzle: storage colelem = col ^ ((row&7)<<3)  (involution), applied by
  // pre-swizzling the GLOBAL source column (rule 21: linear dest + inv-swz src).
  int rows[4], csw[4];
#pragma unroll
  for (int q = 0; q < 4; ++q) {
    int ci = (w * 4 + q) * 64 + l;
    rows[q] = ci >> 3;
    csw[q] = ((ci & 7) * 8) ^ ((rows[q] & 7) << 3);
  }

#define STAGE(bufi, k0)                                                        \
  {                                                                            \
    _Pragma("unroll") for (int q = 0; q < 4; ++q) {                            \
      const unsigned short* ga =                                               \
          Xbf + (size_t)(m0 + rows[q]) * 768 + (k0) + csw[q];                  \
      gl_lds16(ga, &sA[bufi][(w * 4 + q) * 512]);                              \
      const unsigned short* gb =                                               \
          Wb + (size_t)(n0 + rows[q]) * 768 + (k0) + csw[q];                   \
      gl_lds16(gb, &sB[bufi][(w * 4 + q) * 512]);                              \
    }                                                                          \
  }

  STAGE(0, 0);
  __syncthreads();

  int xorr = (l16 & 7) << 3;  // read-side swizzle (row&7 == l16&7)
  for (int kt = 0; kt < 12; ++kt) {
    int cur = kt & 1;
    if (kt < 11) STAGE(cur ^ 1, (kt + 1) * 64);  // prefetch next tile (issue-early)
#pragma unroll
    for (int kk = 0; kk < 2; ++kk) {
      int coff = (kk * 32 + l4 * 8) ^ xorr;
      bf16x8 af[4], bfr[4];
#pragma unroll
      for (int am = 0; am < 4; ++am)
        af[am] = *reinterpret_cast<const bf16x8*>(
            &sA[cur][(wr * 64 + am * 16 + l16) * 64 + coff]);
#pragma unroll
      for (int bn = 0; bn < 4; ++bn)
        bfr[bn] = *reinterpret_cast<const bf16x8*>(
            &sB[cur][(wc * 64 + bn * 16 + l16) * 64 + coff]);
#pragma unroll
      for (int am = 0; am < 4; ++am)
#pragma unroll
        for (int bn = 0; bn < 4; ++bn)
          acc[am][bn] = __builtin_amdgcn_mfma_f32_16x16x32_bf16(af[am], bfr[bn], acc[am][bn], 0, 0, 0);
    }
    __syncthreads();  // drains vmcnt -> prefetched buffer complete for next iter
  }

  // epilogue: C/D layout col = lane&15, row = (lane>>4)*4 + reg
  float bias[4];
#pragma unroll
  for (int bn = 0; bn < 4; ++bn) bias[bn] = base_b[n0 + wc * 64 + bn * 16 + l16];
#pragma unroll
  for (int am = 0; am < 4; ++am) {
    int rbase = m0 + wr * 64 + am * 16 + l4 * 4;
#pragma unroll
    for (int r = 0; r < 4; ++r) {
      float* op = out + (size_t)(rbase + r) * 768 + n0 + wc * 64 + l16;
#pragma unroll
      for (int bn = 0; bn < 4; ++bn) op[bn * 16] = acc[am][bn][r] + bias[bn];
    }
  }
#undef STAGE
}

extern "C" void kernel_launch(void* const* d_in, const int* in_sizes, int n_in,
                              void* d_out, int out_size, void* d_ws, size_t ws_size,
                              hipStream_t stream) {
  const float* X  = (const float*)d_in[0];
  const float* rw = (const float*)d_in[1];
  const float* rb = (const float*)d_in[2];
  const float* bw = (const float*)d_in[3];
  const float* bb = (const float*)d_in[4];
  const float* c0 = (const float*)d_in[5];
  const float* c1 = (const float*)d_in[6];
  const float* c2 = (const float*)d_in[7];
  const float* c3 = (const float*)d_in[8];
  const float* c4 = (const float*)d_in[9];
  const float* c5 = (const float*)d_in[10];
  float* out = (float*)d_out;

  char* ws = (char*)d_ws;
  int* expert        = (int*)(ws + 0);               // 128 B
  float* Kmat        = (float*)(ws + 4096);          // 96 KB
  float* Lt          = (float*)(ws + 102400);        // 96 KB
  // partial (32*16*768*4 = 1.5 MB) unions with Wbt (4.5 MB): partial is fully
  // consumed by k_router_pick before k_build_w writes Wbt.
  float* partial      = (float*)(ws + 262144);
  unsigned short* Wbt = (unsigned short*)(ws + 262144);
  unsigned short* Xbf = (unsigned short*)(ws + 4980736);  // 24 MB

  k_router_pool<<<512, 192, 0, stream>>>(X, Xbf, partial);
  k_router_pick<<<32, 256, 0, stream>>>(partial, rw, rb, expert);
  k_build_kl<<<4, 256, 0, stream>>>(c0, c1, c2, c3, c4, c5, Kmat, Lt);
  k_build_w<<<dim3(768, 4), 256, 0, stream>>>(bw, Kmat, Lt, Wbt);
  k_gemm<<<768, 256, 0, stream>>>(Xbf, Wbt, expert, bb, out);
}

// Round 7
// 64.836 us; speedup vs baseline: 1.6013x; 1.1654x over previous
//
#include <hip/hip_runtime.h>
#include <hip/hip_bf16.h>
#include <stdint.h>

#define GAS __attribute__((address_space(1)))
#define LAS __attribute__((address_space(3)))

typedef __attribute__((ext_vector_type(8))) short bf16x8;
typedef __attribute__((ext_vector_type(4))) float f32x4;

struct us4 { unsigned short x, y, z, w; };

__device__ __forceinline__ void gl_lds16(const void* g, void* lds) {
  __builtin_amdgcn_global_load_lds((const GAS unsigned int*)(uintptr_t)g,
                                   (LAS unsigned int*)(uintptr_t)lds, 16, 0, 0);
}

__device__ __forceinline__ unsigned short f2bf(float f) {
  unsigned u = __float_as_uint(f);
  return (unsigned short)((u + 0x7fffu + ((u >> 16) & 1u)) >> 16);
}

// ---------------- Threefry2x32 (JAX key = (0, 42)) ----------------
__device__ __forceinline__ void threefry2x32_42(unsigned x0, unsigned x1,
                                                unsigned* o0, unsigned* o1) {
  const unsigned k0 = 0u, k1 = 42u;
  unsigned ks[3] = {k0, k1, k0 ^ k1 ^ 0x1BD11BDAu};
  x0 += ks[0]; x1 += ks[1];
  const int rot[2][4] = {{13, 15, 26, 6}, {17, 29, 16, 24}};
#pragma unroll
  for (int i = 0; i < 5; ++i) {
#pragma unroll
    for (int j = 0; j < 4; ++j) {
      int r = rot[i & 1][j];
      x0 += x1;
      x1 = (x1 << r) | (x1 >> (32 - r));
      x1 ^= x0;
    }
    x0 += ks[(i + 1) % 3];
    x1 += ks[(i + 2) % 3] + (unsigned)(i + 1);
  }
  *o0 = x0; *o1 = x1;
}

// ---------------- k1: streaming X->bf16 + per-chunk LOGIT partials ----------------
// 512 blocks: b = blk>>4, c = blk&15 (32 rows). 192 threads, 4 cols each.
__global__ __launch_bounds__(192) void k_router_pool(
    const float* __restrict__ X, const float* __restrict__ rw,
    unsigned short* __restrict__ Xbf, float* __restrict__ partial) {
  int t = threadIdx.x;
  int b = blockIdx.x >> 4, c = blockIdx.x & 15;
  int r0 = b * 512 + c * 32;
  const float* xp = X + (size_t)r0 * 768 + t * 4;
  unsigned short* xo = Xbf + (size_t)r0 * 768 + t * 4;
  float4 acc = {0.f, 0.f, 0.f, 0.f};
#pragma unroll 8
  for (int r = 0; r < 32; ++r) {
    float4 v = *reinterpret_cast<const float4*>(xp + (size_t)r * 768);
    acc.x += v.x; acc.y += v.y; acc.z += v.z; acc.w += v.w;
    us4 o;
    o.x = f2bf(v.x); o.y = f2bf(v.y); o.z = f2bf(v.z); o.w = f2bf(v.w);
    *reinterpret_cast<us4*>(xo + (size_t)r * 768) = o;
  }
  // dot with router rows -> 4 logit partials
  float lp[4];
#pragma unroll
  for (int e = 0; e < 4; ++e) {
    float4 w4 = *reinterpret_cast<const float4*>(rw + e * 768 + t * 4);
    lp[e] = acc.x * w4.x + acc.y * w4.y + acc.z * w4.z + acc.w * w4.w;
  }
#pragma unroll
  for (int off = 32; off > 0; off >>= 1) {
#pragma unroll
    for (int e = 0; e < 4; ++e) lp[e] += __shfl_down(lp[e], off);
  }
  __shared__ float red[3][4];
  int w = t >> 6;
  if ((t & 63) == 0) {
#pragma unroll
    for (int e = 0; e < 4; ++e) red[w][e] = lp[e];
  }
  __syncthreads();
  if (t < 4) partial[blockIdx.x * 4 + t] = red[0][t] + red[1][t] + red[2][t];
}

// ---------------- k2: merged TT-contract + W build (+ router pick in block 0) ----
// grid (48, 4): blockIdx.x = jc (16 N-rows), blockIdx.y = e.
__global__ __launch_bounds__(256) void k_build(
    const float* __restrict__ c0, const float* __restrict__ c1,
    const float* __restrict__ c2, const float* __restrict__ c3,
    const float* __restrict__ c4, const float* __restrict__ c5,
    const float* __restrict__ bw, const float* __restrict__ partial,
    const float* __restrict__ rb, int* __restrict__ expert,
    unsigned short* __restrict__ Wbt) {
  int e = blockIdx.y, jc = blockIdx.x, t = threadIdx.x;

  // --- router pick (block (0,0), threads 0..127; barrier-free) ---
  if (jc == 0 && e == 0 && t < 128) {
    int b = t >> 2, ee = t & 3;
    float s = 0.f;
#pragma unroll
    for (int c = 0; c < 16; ++c) s += partial[(b * 16 + c) * 4 + ee];
    float lg = s * (1.0f / 512.0f) + rb[ee];
    int idx = b * 4 + ee;
    unsigned x0, x1;
    threefry2x32_42(0u, (unsigned)idx, &x0, &x1);
    unsigned bits = x0 ^ x1;  // JAX partitionable: XOR fold of cipher block
    float u01 = __uint_as_float((bits >> 9) | 0x3f800000u) - 1.0f;
    float u = u01 * ((1.0f - 1e-6f) - 1e-6f) + 1e-6f;
    u = fmaxf(u, 1e-6f);
    float v = lg + (-logf(-logf(u)));
    int bi = ee;
#pragma unroll
    for (int off = 1; off < 4; off <<= 1) {
      float vo = __shfl_xor(v, off);
      int io = __shfl_xor(bi, off);
      if (vo > v || (vo == v && io < bi)) { v = vo; bi = io; }
    }
    if (ee == 0) expert[b] = bi;
  }

  __shared__ float KA[768];    // [96 (a1*12+a0)][8 p2]
  __shared__ float LB[768];    // [8 p4][96 (n2*12+n3)]
  __shared__ float Kt[6144];   // [8 p3][768 i]  (p-major: conflict-free reads)
  __shared__ float LtS[128];   // [16 local j][8 p3]

  for (int q = t; q < 768; q += 256) {
    int bc = q >> 3, p2 = q & 7;
    int b2 = bc / 12, cc = bc % 12;
    float s = 0.f;
#pragma unroll
    for (int p1 = 0; p1 < 8; ++p1)
      s += c0[e * 96 + cc * 8 + p1] * c1[((e * 8 + p1) * 8 + b2) * 8 + p2];
    KA[q] = s;
    int p4 = q / 96, mm = q % 96;
    int n2 = mm / 12, n3 = mm % 12;
    float s2 = 0.f;
#pragma unroll
    for (int p5 = 0; p5 < 8; ++p5)
      s2 += c4[((e * 8 + p4) * 8 + n2) * 8 + p5] * c5[(e * 8 + p5) * 12 + n3];
    LB[q] = s2;
  }
  __syncthreads();
  for (int q = t; q < 6144; q += 256) {
    int i = q >> 3, p3 = q & 7;
    int a = i / 96, bc = i % 96;
    float s = 0.f;
#pragma unroll
    for (int p2 = 0; p2 < 8; ++p2)
      s += KA[bc * 8 + p2] * c2[((e * 8 + p2) * 8 + a) * 8 + p3];
    Kt[p3 * 768 + i] = s;
  }
  if (t < 128) {
    int i = t >> 3, p3 = t & 7;
    int j = jc * 16 + i;
    int n1 = j / 96, mm = j % 96;
    float s2 = 0.f;
#pragma unroll
    for (int p4 = 0; p4 < 8; ++p4)
      s2 += c3[((e * 8 + p3) * 8 + n1) * 8 + p4] * LB[p4 * 96 + mm];
    LtS[i * 8 + p3] = s2;
  }
  __syncthreads();
  // W chunk: 16 rows x 768 cols
  for (int idx = t; idx < 12288; idx += 256) {
    int jl = idx / 768, i = idx - jl * 768;
    int j = jc * 16 + jl;
    float s = 0.f;
#pragma unroll
    for (int p = 0; p < 8; ++p) s += Kt[p * 768 + i] * LtS[jl * 8 + p];
    float val = bw[(size_t)j * 768 + i] + 16.0f * s;
    Wbt[(size_t)e * 589824 + (size_t)j * 768 + i] = f2bf(val);
  }
}

// ---------------- k4: bf16 MFMA GEMM, 128x128, BK=64, dbuf + T2 swizzle + XCD remap ----------
// C[t, j] = sum_k Xbf[t, k] * Wbt[e][j][k] + base_b[j]
__global__ __launch_bounds__(256) void k_gemm(
    const unsigned short* __restrict__ Xbf,  // [16384][768]
    const unsigned short* __restrict__ Wbt,  // [4][768][768] (N-major)
    const int* __restrict__ expert,          // [32]
    const float* __restrict__ base_b,        // [768]
    float* __restrict__ out)                 // [16384][768]
{
  __shared__ unsigned short sA[2][8192];
  __shared__ unsigned short sB[2][8192];
  int tid = threadIdx.x;
  int w = tid >> 6, l = tid & 63;
  int l16 = l & 15, l4 = l >> 4;

  // XCD-locality remap (768 = 8*96, bijective).
  int bid = blockIdx.x;
  int work = (bid & 7) * 96 + (bid >> 3);
  int mtile = work / 6, ntile = work - mtile * 6;
  int m0 = mtile * 128, n0 = ntile * 128;
  int e = expert[mtile >> 2];
  const unsigned short* Wb = Wbt + (size_t)e * 589824;
  int wr = w >> 1, wc = w & 1;

  f32x4 acc[4][4];
#pragma unroll
  for (int i = 0; i < 4; ++i)
#pragma unroll
    for (int jj = 0; jj < 4; ++jj) acc[i][jj] = (f32x4)0.f;

  // T2 swizzle via pre-swizzled GLOBAL source + swizzled read (rule 21).
  int rows[4], csw[4];
#pragma unroll
  for (int q = 0; q < 4; ++q) {
    int ci = (w * 4 + q) * 64 + l;
    rows[q] = ci >> 3;
    csw[q] = ((ci & 7) * 8) ^ ((rows[q] & 7) << 3);
  }

#define STAGE(bufi, k0)                                                        \
  {                                                                            \
    _Pragma("unroll") for (int q = 0; q < 4; ++q) {                            \
      const unsigned short* ga =                                               \
          Xbf + (size_t)(m0 + rows[q]) * 768 + (k0) + csw[q];                  \
      gl_lds16(ga, &sA[bufi][(w * 4 + q) * 512]);                              \
      const unsigned short* gb =                                               \
          Wb + (size_t)(n0 + rows[q]) * 768 + (k0) + csw[q];                   \
      gl_lds16(gb, &sB[bufi][(w * 4 + q) * 512]);                              \
    }                                                                          \
  }

  STAGE(0, 0);
  __syncthreads();

  int xorr = (l16 & 7) << 3;  // read-side swizzle
  for (int kt = 0; kt < 12; ++kt) {
    int cur = kt & 1;
    if (kt < 11) STAGE(cur ^ 1, (kt + 1) * 64);  // prefetch next tile
#pragma unroll
    for (int kk = 0; kk < 2; ++kk) {
      int coff = (kk * 32 + l4 * 8) ^ xorr;
      bf16x8 af[4], bfr[4];
#pragma unroll
      for (int am = 0; am < 4; ++am)
        af[am] = *reinterpret_cast<const bf16x8*>(
            &sA[cur][(wr * 64 + am * 16 + l16) * 64 + coff]);
#pragma unroll
      for (int bn = 0; bn < 4; ++bn)
        bfr[bn] = *reinterpret_cast<const bf16x8*>(
            &sB[cur][(wc * 64 + bn * 16 + l16) * 64 + coff]);
      // Swapped operands: reg-dim = n (4 consecutive cols/thread), lane-dim = m.
#pragma unroll
      for (int am = 0; am < 4; ++am)
#pragma unroll
        for (int bn = 0; bn < 4; ++bn)
          acc[am][bn] = __builtin_amdgcn_mfma_f32_16x16x32_bf16(bfr[bn], af[am], acc[am][bn], 0, 0, 0);
    }
    __syncthreads();
  }

  // epilogue: D[row=reg -> n][col=lane -> m]:
  //   n = n0 + wc*64 + bn*16 + l4*4 + r,  m = m0 + wr*64 + am*16 + l16
  f32x4 bb4[4];
#pragma unroll
  for (int bn = 0; bn < 4; ++bn)
    bb4[bn] = *reinterpret_cast<const f32x4*>(base_b + n0 + wc * 64 + bn * 16 + l4 * 4);
#pragma unroll
  for (int am = 0; am < 4; ++am) {
    int m = m0 + wr * 64 + am * 16 + l16;
    float* op = out + (size_t)m * 768 + n0 + wc * 64 + l4 * 4;
#pragma unroll
    for (int bn = 0; bn < 4; ++bn) {
      f32x4 v = acc[am][bn] + bb4[bn];
      __builtin_nontemporal_store(v, reinterpret_cast<f32x4*>(op + bn * 16));
    }
  }
#undef STAGE
}

extern "C" void kernel_launch(void* const* d_in, const int* in_sizes, int n_in,
                              void* d_out, int out_size, void* d_ws, size_t ws_size,
                              hipStream_t stream) {
  const float* X  = (const float*)d_in[0];
  const float* rw = (const float*)d_in[1];
  const float* rb = (const float*)d_in[2];
  const float* bw = (const float*)d_in[3];
  const float* bb = (const float*)d_in[4];
  const float* c0 = (const float*)d_in[5];
  const float* c1 = (const float*)d_in[6];
  const float* c2 = (const float*)d_in[7];
  const float* c3 = (const float*)d_in[8];
  const float* c4 = (const float*)d_in[9];
  const float* c5 = (const float*)d_in[10];
  float* out = (float*)d_out;

  char* ws = (char*)d_ws;
  int* expert         = (int*)(ws + 0);               // 128 B
  float* partial      = (float*)(ws + 4096);          // 512*4*4 = 8 KB
  unsigned short* Wbt = (unsigned short*)(ws + 262144);   // 4.5 MB
  unsigned short* Xbf = (unsigned short*)(ws + 4980736);  // 24 MB

  k_router_pool<<<512, 192, 0, stream>>>(X, rw, Xbf, partial);
  k_build<<<dim3(48, 4), 256, 0, stream>>>(c0, c1, c2, c3, c4, c5, bw,
                                           partial, rb, expert, Wbt);
  k_gemm<<<768, 256, 0, stream>>>(Xbf, Wbt, expert, bb, out);
}

// Round 9
// 58.848 us; speedup vs baseline: 1.7643x; 1.1018x over previous
//
#include <hip/hip_runtime.h>
#include <hip/hip_bf16.h>
#include <stdint.h>

#define GAS __attribute__((address_space(1)))
#define LAS __attribute__((address_space(3)))

typedef __attribute__((ext_vector_type(8))) short bf16x8;
typedef __attribute__((ext_vector_type(4))) float f32x4;

struct us4 { unsigned short x, y, z, w; };

__device__ __forceinline__ void gl_lds16(const void* g, void* lds) {
  __builtin_amdgcn_global_load_lds((const GAS unsigned int*)(uintptr_t)g,
                                   (LAS unsigned int*)(uintptr_t)lds, 16, 0, 0);
}

__device__ __forceinline__ unsigned short f2bf(float f) {
  unsigned u = __float_as_uint(f);
  return (unsigned short)((u + 0x7fffu + ((u >> 16) & 1u)) >> 16);
}

// ---------------- Threefry2x32 (JAX key = (0, 42)) ----------------
__device__ __forceinline__ void threefry2x32_42(unsigned x0, unsigned x1,
                                                unsigned* o0, unsigned* o1) {
  const unsigned k0 = 0u, k1 = 42u;
  unsigned ks[3] = {k0, k1, k0 ^ k1 ^ 0x1BD11BDAu};
  x0 += ks[0]; x1 += ks[1];
  const int rot[2][4] = {{13, 15, 26, 6}, {17, 29, 16, 24}};
#pragma unroll
  for (int i = 0; i < 5; ++i) {
#pragma unroll
    for (int j = 0; j < 4; ++j) {
      int r = rot[i & 1][j];
      x0 += x1;
      x1 = (x1 << r) | (x1 >> (32 - r));
      x1 ^= x0;
    }
    x0 += ks[(i + 1) % 3];
    x1 += ks[(i + 2) % 3] + (unsigned)(i + 1);
  }
  *o0 = x0; *o1 = x1;
}

// ========== kernel A: heterogeneous — blocks 0..191 build Wbt, 192..703 pool ==========
__global__ __launch_bounds__(256) void k_prep(
    const float* __restrict__ X, const float* __restrict__ rw,
    const float* __restrict__ bw,
    const float* __restrict__ c0, const float* __restrict__ c1,
    const float* __restrict__ c2, const float* __restrict__ c3,
    const float* __restrict__ c4, const float* __restrict__ c5,
    unsigned short* __restrict__ Xbf, float* __restrict__ partial,
    unsigned short* __restrict__ Wbt) {
  __shared__ __align__(16) char smem[31232];
  int t = threadIdx.x;
  int bid = blockIdx.x;

  if (bid < 192) {
    // ---- build Wbt[e][j][i] = bf16(bw[j][i] + 16*(K L)[i][j]) ----
    int e = bid / 48, jc = bid % 48;
    float* KA = (float*)smem;            // [96][8]
    float* LB = (float*)(smem + 3072);   // [8][96]
    float* Kt = (float*)(smem + 6144);   // [8 p3][768 i]
    float* LtS = (float*)(smem + 30720); // [16 j][8 p3]
    for (int q = t; q < 768; q += 256) {
      int bc = q >> 3, p2 = q & 7;
      int b2 = bc / 12, cc = bc % 12;
      float s = 0.f;
#pragma unroll
      for (int p1 = 0; p1 < 8; ++p1)
        s += c0[e * 96 + cc * 8 + p1] * c1[((e * 8 + p1) * 8 + b2) * 8 + p2];
      KA[q] = s;
      int p4 = q / 96, mm = q % 96;
      int n2 = mm / 12, n3 = mm % 12;
      float s2 = 0.f;
#pragma unroll
      for (int p5 = 0; p5 < 8; ++p5)
        s2 += c4[((e * 8 + p4) * 8 + n2) * 8 + p5] * c5[(e * 8 + p5) * 12 + n3];
      LB[q] = s2;
    }
    __syncthreads();
    for (int q = t; q < 6144; q += 256) {
      int i = q >> 3, p3 = q & 7;
      int a = i / 96, bc = i % 96;
      float s = 0.f;
#pragma unroll
      for (int p2 = 0; p2 < 8; ++p2)
        s += KA[bc * 8 + p2] * c2[((e * 8 + p2) * 8 + a) * 8 + p3];
      Kt[p3 * 768 + i] = s;
    }
    if (t < 128) {
      int i = t >> 3, p3 = t & 7;
      int j = jc * 16 + i;
      int n1 = j / 96, mm = j % 96;
      float s2 = 0.f;
#pragma unroll
      for (int p4 = 0; p4 < 8; ++p4)
        s2 += c3[((e * 8 + p3) * 8 + n1) * 8 + p4] * LB[p4 * 96 + mm];
      LtS[i * 8 + p3] = s2;
    }
    __syncthreads();
    for (int idx = t; idx < 12288; idx += 256) {
      int jl = idx / 768, i = idx - jl * 768;
      int j = jc * 16 + jl;
      float s = 0.f;
#pragma unroll
      for (int p = 0; p < 8; ++p) s += Kt[p * 768 + i] * LtS[jl * 8 + p];
      float val = bw[(size_t)j * 768 + i] + 16.0f * s;
      Wbt[(size_t)e * 589824 + (size_t)j * 768 + i] = f2bf(val);
    }
  } else {
    // ---- pool: X -> bf16 + logit partials; 512 chunks of 32 rows ----
    float* red = (float*)smem;  // [3][4]
    int p = bid - 192;
    int r0 = p * 32;  // p = b*16 + c, rows are contiguous anyway
    float lp0 = 0.f, lp1 = 0.f, lp2 = 0.f, lp3 = 0.f;
    if (t < 192) {
      const float* xp = X + (size_t)r0 * 768 + t * 4;
      unsigned short* xo = Xbf + (size_t)r0 * 768 + t * 4;
      float4 acc = {0.f, 0.f, 0.f, 0.f};
#pragma unroll 8
      for (int r = 0; r < 32; ++r) {
        float4 v = *reinterpret_cast<const float4*>(xp + (size_t)r * 768);
        acc.x += v.x; acc.y += v.y; acc.z += v.z; acc.w += v.w;
        us4 o;
        o.x = f2bf(v.x); o.y = f2bf(v.y); o.z = f2bf(v.z); o.w = f2bf(v.w);
        *reinterpret_cast<us4*>(xo + (size_t)r * 768) = o;
      }
      float4 w0 = *reinterpret_cast<const float4*>(rw + 0 * 768 + t * 4);
      float4 w1 = *reinterpret_cast<const float4*>(rw + 1 * 768 + t * 4);
      float4 w2 = *reinterpret_cast<const float4*>(rw + 2 * 768 + t * 4);
      float4 w3 = *reinterpret_cast<const float4*>(rw + 3 * 768 + t * 4);
      lp0 = acc.x * w0.x + acc.y * w0.y + acc.z * w0.z + acc.w * w0.w;
      lp1 = acc.x * w1.x + acc.y * w1.y + acc.z * w1.z + acc.w * w1.w;
      lp2 = acc.x * w2.x + acc.y * w2.y + acc.z * w2.z + acc.w * w2.w;
      lp3 = acc.x * w3.x + acc.y * w3.y + acc.z * w3.z + acc.w * w3.w;
    }
#pragma unroll
    for (int off = 32; off > 0; off >>= 1) {
      lp0 += __shfl_down(lp0, off);
      lp1 += __shfl_down(lp1, off);
      lp2 += __shfl_down(lp2, off);
      lp3 += __shfl_down(lp3, off);
    }
    int w = t >> 6;
    if ((t & 63) == 0 && w < 3) {
      red[w * 4 + 0] = lp0; red[w * 4 + 1] = lp1;
      red[w * 4 + 2] = lp2; red[w * 4 + 3] = lp3;
    }
    __syncthreads();
    if (t < 4) partial[p * 4 + t] = red[0 + t] + red[4 + t] + red[8 + t];
  }
}

// ========== kernel B: expert-pick (per block, from partials) + MFMA GEMM ==========
// C[t, j] = sum_k Xbf[t, k] * Wbt[e][j][k] + base_b[j]
__global__ __launch_bounds__(256, 4) void k_gemm(
    const unsigned short* __restrict__ Xbf,  // [16384][768]
    const unsigned short* __restrict__ Wbt,  // [4][768][768] (N-major)
    const float* __restrict__ partial,       // [512][4]
    const float* __restrict__ rb,            // [4]
    const float* __restrict__ base_b,        // [768]
    float* __restrict__ out)                 // [16384][768]
{
  __shared__ unsigned short sA[128 * 64];
  __shared__ unsigned short sB[128 * 64];
  __shared__ int sExp;
  int t = threadIdx.x;
  int w = t >> 6, l = t & 63;
  int l16 = l & 15, l4 = l >> 4;

  // XCD-locality remap (768 = 8*96, bijective)
  int bid = blockIdx.x;
  int work = (bid & 7) * 96 + (bid >> 3);
  int mtile = work / 6, ntile = work - mtile * 6;
  int m0 = mtile * 128, n0 = ntile * 128;
  int b = mtile >> 2;  // batch

  // --- per-block expert pick (lanes 0..3; deterministic across blocks) ---
  if (t < 4) {
    float s = 0.f;
#pragma unroll
    for (int c = 0; c < 16; ++c) s += partial[(b * 16 + c) * 4 + t];
    float lg = s * (1.0f / 512.0f) + rb[t];
    int idx = b * 4 + t;
    unsigned x0, x1;
    threefry2x32_42(0u, (unsigned)idx, &x0, &x1);
    unsigned bits = x0 ^ x1;  // JAX partitionable: XOR fold of cipher block
    float u01 = __uint_as_float((bits >> 9) | 0x3f800000u) - 1.0f;
    float u = u01 * ((1.0f - 1e-6f) - 1e-6f) + 1e-6f;
    u = fmaxf(u, 1e-6f);
    float v = lg + (-logf(-logf(u)));
    int bi = t;
#pragma unroll
    for (int off = 1; off < 4; off <<= 1) {
      float vo = __shfl_xor(v, off);
      int io = __shfl_xor(bi, off);
      if (vo > v || (vo == v && io < bi)) { v = vo; bi = io; }
    }
    if (t == 0) sExp = bi;
  }
  __syncthreads();
  int e = sExp;
  const unsigned short* Wb = Wbt + (size_t)e * 589824;
  int wr = w >> 1, wc = w & 1;

  f32x4 acc[4][4];
#pragma unroll
  for (int i = 0; i < 4; ++i)
#pragma unroll
    for (int jj = 0; jj < 4; ++jj) acc[i][jj] = (f32x4)0.f;

  // T2 swizzle via pre-swizzled GLOBAL source + swizzled read (rule 21).
  int rows[4], csw[4];
#pragma unroll
  for (int q = 0; q < 4; ++q) {
    int ci = (w * 4 + q) * 64 + l;
    rows[q] = ci >> 3;
    csw[q] = ((ci & 7) * 8) ^ ((rows[q] & 7) << 3);
  }

  int xorr = (l16 & 7) << 3;  // read-side swizzle
  for (int k0 = 0; k0 < 768; k0 += 64) {
#pragma unroll
    for (int q = 0; q < 4; ++q) {
      const unsigned short* ga = Xbf + (size_t)(m0 + rows[q]) * 768 + k0 + csw[q];
      gl_lds16(ga, &sA[(w * 4 + q) * 512]);
      const unsigned short* gb = Wb + (size_t)(n0 + rows[q]) * 768 + k0 + csw[q];
      gl_lds16(gb, &sB[(w * 4 + q) * 512]);
    }
    __syncthreads();
#pragma unroll
    for (int kk = 0; kk < 2; ++kk) {
      int coff = (kk * 32 + l4 * 8) ^ xorr;
      bf16x8 af[4], bfr[4];
#pragma unroll
      for (int am = 0; am < 4; ++am)
        af[am] = *reinterpret_cast<const bf16x8*>(
            &sA[(wr * 64 + am * 16 + l16) * 64 + coff]);
#pragma unroll
      for (int bn = 0; bn < 4; ++bn)
        bfr[bn] = *reinterpret_cast<const bf16x8*>(
            &sB[(wc * 64 + bn * 16 + l16) * 64 + coff]);
      // Swapped operands: reg-dim = n (coalesced stores), lane-dim = m.
#pragma unroll
      for (int am = 0; am < 4; ++am)
#pragma unroll
        for (int bn = 0; bn < 4; ++bn)
          acc[am][bn] = __builtin_amdgcn_mfma_f32_16x16x32_bf16(
              bfr[bn], af[am], acc[am][bn], 0, 0, 0);
    }
    __syncthreads();
  }

  // epilogue: n = n0 + wc*64 + bn*16 + l4*4 + r, m = m0 + wr*64 + am*16 + l16
  f32x4 bb4[4];
#pragma unroll
  for (int bn = 0; bn < 4; ++bn)
    bb4[bn] = *reinterpret_cast<const f32x4*>(base_b + n0 + wc * 64 + bn * 16 + l4 * 4);
#pragma unroll
  for (int am = 0; am < 4; ++am) {
    int m = m0 + wr * 64 + am * 16 + l16;
    float* op = out + (size_t)m * 768 + n0 + wc * 64 + l4 * 4;
#pragma unroll
    for (int bn = 0; bn < 4; ++bn) {
      f32x4 v = acc[am][bn] + bb4[bn];
      __builtin_nontemporal_store(v, reinterpret_cast<f32x4*>(op + bn * 16));
    }
  }
}

extern "C" void kernel_launch(void* const* d_in, const int* in_sizes, int n_in,
                              void* d_out, int out_size, void* d_ws, size_t ws_size,
                              hipStream_t stream) {
  const float* X  = (const float*)d_in[0];
  const float* rw = (const float*)d_in[1];
  const float* rb = (const float*)d_in[2];
  const float* bw = (const float*)d_in[3];
  const float* bb = (const float*)d_in[4];
  const float* c0 = (const float*)d_in[5];
  const float* c1 = (const float*)d_in[6];
  const float* c2 = (const float*)d_in[7];
  const float* c3 = (const float*)d_in[8];
  const float* c4 = (const float*)d_in[9];
  const float* c5 = (const float*)d_in[10];
  float* out = (float*)d_out;

  char* ws = (char*)d_ws;
  float* partial      = (float*)(ws + 4096);              // 512*4*4 = 8 KB
  unsigned short* Wbt = (unsigned short*)(ws + 262144);   // 4.5 MB
  unsigned short* Xbf = (unsigned short*)(ws + 4980736);  // 24 MB

  k_prep<<<704, 256, 0, stream>>>(X, rw, bw, c0, c1, c2, c3, c4, c5,
                                  Xbf, partial, Wbt);
  k_gemm<<<768, 256, 0, stream>>>(Xbf, Wbt, partial, rb, bb, out);
}